// Round 12
// baseline (250.620 us; speedup 1.0000x reference)
//
#include <hip/hip_runtime.h>
#include <hip/hip_bf16.h>

// BatchSplitFF: DM=1024, NEXPERTS=32, SETS=4 (ES=128 pairs), ESIZE=32, B=2, S=8192
#define DM   1024
#define NES  128
#define GT   32
#define NGRP 512
#define FSZ  32
#define MARGIN_EPS 1e-3f   // > 4x deterministic bound on 3-term bf16-split error

typedef float f32x4 __attribute__((ext_vector_type(4)));
typedef short s16x8 __attribute__((ext_vector_type(8)));

__device__ inline unsigned short f2bf(float f) {   // RNE f32->bf16
  union { float f; unsigned int u; } x; x.f = f;
  unsigned int r = x.u + 0x7fffu + ((x.u >> 16) & 1u);
  return (unsigned short)(r >> 16);
}
__device__ inline float bf2f(unsigned short h) {
  union { unsigned int u; float f; } x; x.u = ((unsigned int)h) << 16;
  return x.f;
}

// ---------------------------------------------------------------------------
// kW: merged weight repack. [0,2048): W1 -> bf16 B-frag (K=d, N=f).
// [2048,4096): W2 -> bf16 B-frag (K=f, N=d). [4096,4160): Wc -> hi/lo bf16
// B-frag (K=d, N=es). Unchanged (proven).
// ---------------------------------------------------------------------------
__global__ __launch_bounds__(256) void kW(const float* __restrict__ W1,
                                          const float* __restrict__ W2,
                                          const float* __restrict__ Wc,
                                          unsigned short* __restrict__ W1f,
                                          unsigned short* __restrict__ W2f,
                                          unsigned short* __restrict__ Wchf,
                                          unsigned short* __restrict__ Wclf) {
  const int bid = blockIdx.x;
  if (bid < 2048) {
    int idx = bid * 256 + threadIdx.x;             // (es, kt, nh, lane)
    int l = idx & 63, nh = (idx >> 6) & 1, kt = (idx >> 7) & 31, es = idx >> 12;
    const float* src = W1 + ((size_t)es * DM + kt * 32 + (l >> 4) * 8) * FSZ
                          + nh * 16 + (l & 15);
    s16x8 v;
#pragma unroll
    for (int i = 0; i < 8; ++i) v[i] = (short)f2bf(src[(size_t)i * FSZ]);
    *(s16x8*)(W1f + (size_t)idx * 8) = v;
  } else if (bid < 4096) {
    int idx = (bid - 2048) * 256 + threadIdx.x;    // (es, dt, lane)
    int l = idx & 63, dt = (idx >> 6) & 63, es = idx >> 12;
    const float* src = W2 + ((size_t)es * DM + dt * 16 + (l & 15)) * FSZ + (l >> 4) * 8;
    float4 a = *(const float4*)src;
    float4 b = *(const float4*)(src + 4);
    s16x8 v;
    v[0] = (short)f2bf(a.x); v[1] = (short)f2bf(a.y);
    v[2] = (short)f2bf(a.z); v[3] = (short)f2bf(a.w);
    v[4] = (short)f2bf(b.x); v[5] = (short)f2bf(b.y);
    v[6] = (short)f2bf(b.z); v[7] = (short)f2bf(b.w);
    *(s16x8*)(W2f + (size_t)idx * 8) = v;
  } else {
    int idx = (bid - 4096) * 256 + threadIdx.x;    // (kt, nt, lane) in [0,16384)
    int l = idx & 63, nt = (idx >> 6) & 7, kt = idx >> 9;
    const float* src = Wc + (size_t)(kt * 32 + (l >> 4) * 8) * NES + nt * 16 + (l & 15);
    s16x8 h, lo;
#pragma unroll
    for (int i = 0; i < 8; ++i) {
      float v = src[(size_t)i * NES];
      unsigned short hh = f2bf(v);
      h[i]  = (short)hh;
      lo[i] = (short)f2bf(v - bf2f(hh));
    }
    *(s16x8*)(Wchf + (size_t)idx * 8) = h;
    *(s16x8*)(Wclf + (size_t)idx * 8) = lo;
  }
}

// ---------------------------------------------------------------------------
// kLg v4: 16 waves/block (1024 thr), each wave owns a 16t x 16es strip with
// 3 MFMAs/kt (hh, lh, hl -- per-column chain BIT-IDENTICAL to r10/r11: one
// wave per column, kt-sequential). launch_bounds(1024,8) -> 8 waves/SIMD
// (2x r11) for latency hiding; VGPR must stay <=64. Depth-1 reg pipeline.
// ---------------------------------------------------------------------------
__global__ __launch_bounds__(1024, 8) void kLg(const float* __restrict__ x,
                                               const unsigned short* __restrict__ Wchf,
                                               const unsigned short* __restrict__ Wclf,
                                               const float* __restrict__ bc,
                                               unsigned short* __restrict__ xh,
                                               unsigned int* __restrict__ sel,
                                               unsigned int* __restrict__ flags,
                                               unsigned int* __restrict__ cnt) {
  __shared__ float lg[GT * NES];                   // 16 KB
  const int g   = blockIdx.x;
  const int tid = threadIdx.x;
  const int l   = tid & 63, w = tid >> 6;          // 16 waves
  const int wt  = w & 1, we = w >> 1;              // m-tile / es-16-tile [0,8)
  const int r15 = l & 15, q = l >> 4;
  const int row = g * GT + wt * 16 + r15;
  const float* xrow = x + (size_t)row * DM + q * 8;
  unsigned short* xhrow = xh + (size_t)row * DM + q * 8;
  const unsigned short* Bh_base = Wchf + ((size_t)we * 64 + l) * 8;
  const unsigned short* Bl_base = Wclf + ((size_t)we * 64 + l) * 8;
  // per-kt stride in shorts: 8 frag-groups * 64 lanes * 8 = 4096

  f32x4 acc0 = {0.f, 0.f, 0.f, 0.f};

  // pipeline slots (current / next)
  float4 xa = *(const float4*)(xrow);
  float4 xb4 = *(const float4*)(xrow + 4);
  s16x8 Bh0 = *(const s16x8*)(Bh_base);
  s16x8 Bl0 = *(const s16x8*)(Bl_base);

  for (int kt = 0; kt < 32; ++kt) {
    const int ktn = (kt < 31) ? kt + 1 : 31;       // clamped (last iter dummy)
    float4 nxa = *(const float4*)(xrow + ktn * 32);
    float4 nxb = *(const float4*)(xrow + ktn * 32 + 4);
    s16x8 nBh0 = *(const s16x8*)(Bh_base + (size_t)ktn * 4096);
    s16x8 nBl0 = *(const s16x8*)(Bl_base + (size_t)ktn * 4096);

    // convert current x slab to hi/lo bf16
    float v[8] = {xa.x, xa.y, xa.z, xa.w, xb4.x, xb4.y, xb4.z, xb4.w};
    s16x8 Ah, Al;
#pragma unroll
    for (int k = 0; k < 8; ++k) {
      unsigned short h = f2bf(v[k]);
      Ah[k] = (short)h;
      Al[k] = (short)f2bf(v[k] - bf2f(h));
    }
    if (we == 0) *(s16x8*)(xhrow + kt * 32) = Ah;  // xh emission (once/row/kt)

    // MFMA: hh, lh, hl (r9-r11 order, proven)
    acc0 = __builtin_amdgcn_mfma_f32_16x16x32_bf16(Ah, Bh0, acc0, 0, 0, 0);
    acc0 = __builtin_amdgcn_mfma_f32_16x16x32_bf16(Al, Bh0, acc0, 0, 0, 0);
    acc0 = __builtin_amdgcn_mfma_f32_16x16x32_bf16(Ah, Bl0, acc0, 0, 0, 0);

    xa = nxa; xb4 = nxb; Bh0 = nBh0; Bl0 = nBl0;
  }

#pragma unroll
  for (int r = 0; r < 4; ++r) {                    // C/D: row=(lane>>4)*4+reg
    const int t = wt * 16 + q * 4 + r;
    lg[t * NES + we * 16 + r15] = acc0[r];
  }
  __syncthreads();

  if (tid < NES) {                                 // identical to r9-r11 (proven)
    const int es = tid;
    const float bce = bc[es];
    float m1 = -INFINITY, m2 = -INFINITY;
    int am = 0;
    for (int t = 0; t < GT; ++t) {
      float v = (lg[t * NES + es] + bce) + (float)((double)t * (1e-6 / 31.0));
      if (v > m1) { m2 = m1; m1 = v; am = t; }
      else if (v > m2) m2 = v;
    }
    sel[(size_t)g * NES + es] = 1u << am;
    if (!(m1 - m2 > MARGIN_EPS)) {                 // narrow margin (or NaN): exact pass
      unsigned int p = atomicAdd(cnt, 1u);
      flags[p] = ((unsigned int)g << 7) | (unsigned int)es;
    }
  }
}

// ---------------------------------------------------------------------------
// kFix: exact f32 recompute for flagged columns, BIT-IDENTICAL to the r1-r7
// chain (unchanged, proven).
// ---------------------------------------------------------------------------
__global__ __launch_bounds__(64) void kFix(const float* __restrict__ x,
                                           const float* __restrict__ Wc,
                                           const float* __restrict__ bc,
                                           unsigned int* __restrict__ sel,
                                           const unsigned int* __restrict__ flags,
                                           const unsigned int* __restrict__ cnt) {
  __shared__ float v[GT];
  const int tid = threadIdx.x;
  const unsigned int n = *cnt;
  for (unsigned int i = blockIdx.x; i < n; i += gridDim.x) {
    const unsigned int f = flags[i];
    const int g = (int)(f >> 7), es = (int)(f & 127u);
    if (tid < GT) {
      const float* xr = x + ((size_t)g * GT + tid) * DM;
      const float* wcol = Wc + es;
      float acc = 0.f;
      for (int c = 0; c < 16; ++c) {
        float part = 0.f;
#pragma unroll 4
        for (int s = 0; s < 16; ++s) {
          const int d0 = c * 64 + s * 4;
          float4 xv = *(const float4*)&xr[d0];
          float w0 = wcol[(size_t)(d0 + 0) * NES];
          float w1 = wcol[(size_t)(d0 + 1) * NES];
          float w2 = wcol[(size_t)(d0 + 2) * NES];
          float w3 = wcol[(size_t)(d0 + 3) * NES];
          part = fmaf(xv.x, w0, part);             // dd-sequential (r1 order)
          part = fmaf(xv.y, w1, part);
          part = fmaf(xv.z, w2, part);
          part = fmaf(xv.w, w3, part);
        }
        acc += part;
      }
      v[tid] = (acc + bc[es]) + (float)((double)tid * (1e-6 / 31.0));
    }
    __syncthreads();
    if (tid == 0) {
      float m = -INFINITY;
      for (int t = 0; t < GT; ++t) m = fmaxf(m, v[t]);
      unsigned int msk = 0u;
      for (int t = 0; t < GT; ++t) if (v[t] == m) msk |= (1u << t);
      sel[(size_t)g * NES + es] = msk;
    }
    __syncthreads();
  }
}

// ---------------------------------------------------------------------------
// kBm: inner = relu(xsel . W1[es] + b1[es]) via MFMA (unchanged, proven).
// ---------------------------------------------------------------------------
__global__ __launch_bounds__(256, 2) void kBm(const unsigned short* __restrict__ xb,
                                              const unsigned short* __restrict__ W1f,
                                              const float* __restrict__ b1,
                                              const unsigned int* __restrict__ sel,
                                              unsigned short* __restrict__ innerb) {
  __shared__ unsigned short As[128 * 128];   // [row][k] bf16, byte^((row&7)<<4)
  __shared__ int tokL[128];
  __shared__ unsigned int mulL[128];
  const int bid = blockIdx.x;
  const int es = bid >> 2, g0 = (bid & 3) * 128;
  const int tid = threadIdx.x;
  const int l = tid & 63, w = tid >> 6;
  const int r15 = l & 15, q = l >> 4;
  const int mw = w * 32;

  if (tid < 128) {
    unsigned int m = sel[(size_t)(g0 + tid) * NES + es];
    tokL[tid] = (g0 + tid) * GT + (__ffs(m) - 1);
    mulL[tid] = (m & (m - 1)) ? m : 0u;
  }

  const int r = tid >> 1, p = tid & 1;
  const int swz = (r & 7) << 4;
  const unsigned int dbase = (unsigned int)r * 256 + (unsigned int)p * 128;

  f32x4 acc[2][2];
#pragma unroll
  for (int i = 0; i < 2; ++i)
#pragma unroll
    for (int j = 0; j < 2; ++j) acc[i][j] = (f32x4){0.f, 0.f, 0.f, 0.f};

  for (int c = 0; c < 8; ++c) {
    __syncthreads();
    unsigned int mm = mulL[r];
    if (!mm) {
      const unsigned short* src = xb + (size_t)tokL[r] * DM + c * 128 + p * 64;
#pragma unroll
      for (int j = 0; j < 8; ++j) {
        s16x8 v = *(const s16x8*)(src + j * 8);
        *(s16x8*)((char*)As + ((dbase + j * 16) ^ swz)) = v;
      }
    } else {
      size_t grow = (size_t)(g0 + r) * GT;
#pragma unroll
      for (int j = 0; j < 8; ++j) {
        float av[8] = {0.f, 0.f, 0.f, 0.f, 0.f, 0.f, 0.f, 0.f};
        unsigned int m2 = mm;
        while (m2) {
          int tt = __ffs(m2) - 1; m2 &= m2 - 1;
          s16x8 v = *(const s16x8*)(xb + (grow + tt) * DM + c * 128 + p * 64 + j * 8);
#pragma unroll
          for (int k = 0; k < 8; ++k) av[k] += bf2f((unsigned short)v[k]);
        }
        s16x8 o;
#pragma unroll
        for (int k = 0; k < 8; ++k) o[k] = (short)f2bf(av[k]);
        *(s16x8*)((char*)As + ((dbase + j * 16) ^ swz)) = o;
      }
    }
    __syncthreads();

#pragma unroll
    for (int s = 0; s < 4; ++s) {
      const int ks = c * 4 + s;
      const unsigned short* bp = W1f + ((size_t)es * 32 + ks) * 1024 + l * 8;
      s16x8 bf0 = *(const s16x8*)bp;
      s16x8 bf1 = *(const s16x8*)(bp + 512);
      const int row0 = mw + r15, row1 = mw + 16 + r15;
      s16x8 a0 = *(const s16x8*)((char*)As +
                   (((unsigned)row0 * 256 + s * 64 + q * 16) ^ ((row0 & 7) << 4)));
      s16x8 a1 = *(const s16x8*)((char*)As +
                   (((unsigned)row1 * 256 + s * 64 + q * 16) ^ ((row1 & 7) << 4)));
      acc[0][0] = __builtin_amdgcn_mfma_f32_16x16x32_bf16(a0, bf0, acc[0][0], 0, 0, 0);
      acc[0][1] = __builtin_amdgcn_mfma_f32_16x16x32_bf16(a0, bf1, acc[0][1], 0, 0, 0);
      acc[1][0] = __builtin_amdgcn_mfma_f32_16x16x32_bf16(a1, bf0, acc[1][0], 0, 0, 0);
      acc[1][1] = __builtin_amdgcn_mfma_f32_16x16x32_bf16(a1, bf1, acc[1][1], 0, 0, 0);
    }
  }

  float bia0 = b1[es * FSZ + r15];
  float bia1 = b1[es * FSZ + 16 + r15];
#pragma unroll
  for (int i = 0; i < 2; ++i)
#pragma unroll
    for (int rr = 0; rr < 4; ++rr) {
      int g = g0 + mw + i * 16 + q * 4 + rr;
      unsigned short* op = innerb + ((size_t)es * NGRP + g) * FSZ;
      op[r15]      = f2bf(fmaxf(acc[i][0][rr] + bia0, 0.f));
      op[16 + r15] = f2bf(fmaxf(acc[i][1][rr] + bia1, 0.f));
    }
}

// ---------------------------------------------------------------------------
// kC1: per-es dense GEMM (512g x 32f).(32f x 1024d) -> Rb bf16 [g][Ec][d],
// b2 folded (unchanged, proven).
// ---------------------------------------------------------------------------
__global__ __launch_bounds__(256) void kC1(const unsigned short* __restrict__ innerb,
                                           const unsigned short* __restrict__ W2f,
                                           const float* __restrict__ b2,
                                           unsigned short* __restrict__ Rb,
                                           int es0, int Ec) {
  const int bid = blockIdx.x;
  const int esl = bid >> 5;
  const int es  = es0 + esl;
  const int mt  = (bid >> 3) & 3;
  const int nt  = bid & 7;
  const int tid = threadIdx.x;
  const int l = tid & 63, w = tid >> 6;
  const int r15 = l & 15, q = l >> 4;
  const int g0 = mt * 128 + (w >> 1) * 64;
  const int n0 = nt * 128 + (w & 1) * 64;

  const unsigned short* Ab = innerb + ((size_t)es * NGRP + g0 + r15) * FSZ + q * 8;
  const unsigned short* Bb = W2f + (((size_t)es * 64 + (n0 >> 4)) * 64 + l) * 8;
  s16x8 a[4], b[4];
#pragma unroll
  for (int i = 0; i < 4; ++i) a[i] = *(const s16x8*)(Ab + (size_t)i * 16 * FSZ);
#pragma unroll
  for (int j = 0; j < 4; ++j) b[j] = *(const s16x8*)(Bb + (size_t)j * 64 * 8);

  const f32x4 z = {0.f, 0.f, 0.f, 0.f};
  f32x4 acc[4][4];
#pragma unroll
  for (int i = 0; i < 4; ++i)
#pragma unroll
    for (int j = 0; j < 4; ++j)
      acc[i][j] = __builtin_amdgcn_mfma_f32_16x16x32_bf16(a[i], b[j], z, 0, 0, 0);

#pragma unroll
  for (int j = 0; j < 4; ++j) {
    const int col = n0 + j * 16 + r15;
    const float b2v = b2[(size_t)es * DM + col];
#pragma unroll
    for (int i = 0; i < 4; ++i) {
#pragma unroll
      for (int r = 0; r < 4; ++r) {
        const int g = g0 + i * 16 + q * 4 + r;
        Rb[((size_t)g * Ec + esl) * DM + col] = f2bf(acc[i][j][r] + b2v);
      }
    }
  }
}

// ---------------------------------------------------------------------------
// kC2: per-(group, d-quarter) gather-combine (unchanged, proven).
// ---------------------------------------------------------------------------
__global__ __launch_bounds__(256) void kC2(const unsigned short* __restrict__ Rb,
                                           const unsigned int* __restrict__ sel,
                                           float* __restrict__ out,
                                           int es0, int Ec, int direct) {
  __shared__ unsigned int cnt[32];
  __shared__ unsigned char list[32][128];
  const int bid = blockIdx.x;
  const int g = bid >> 2, dq = bid & 3;
  const int tid = threadIdx.x;
  if (tid < 32) cnt[tid] = 0;
  __syncthreads();
  if (tid < Ec) {
    unsigned int m = sel[(size_t)g * NES + es0 + tid];
    while (m) { int t = __ffs(m) - 1; m &= m - 1;
      unsigned int p = atomicAdd(&cnt[t], 1u);
      list[t][p] = (unsigned char)tid; }
  }
  __syncthreads();
  const int t = tid >> 3, part = tid & 7;
  const int d0 = dq * 256 + part * 32;
  const int n = (int)cnt[t];
  const unsigned short* base = Rb + (size_t)g * Ec * DM + d0;

  float acc[32];
#pragma unroll
  for (int i = 0; i < 32; ++i) acc[i] = 0.f;

  s16x8 cur[4];
  if (n) {
    const unsigned short* r = base + (size_t)list[t][0] * DM;
#pragma unroll
    for (int v = 0; v < 4; ++v) cur[v] = *(const s16x8*)(r + v * 8);
  }
  for (int e = 0; e < n; ++e) {
    s16x8 nxt[4];
    const bool more = (e + 1 < n);
    if (more) {
      const unsigned short* r = base + (size_t)list[t][e + 1] * DM;
#pragma unroll
      for (int v = 0; v < 4; ++v) nxt[v] = *(const s16x8*)(r + v * 8);
    }
#pragma unroll
    for (int v = 0; v < 4; ++v)
#pragma unroll
      for (int k = 0; k < 8; ++k)
        acc[v * 8 + k] += bf2f((unsigned short)cur[v][k]);
    if (more) {
#pragma unroll
      for (int v = 0; v < 4; ++v) cur[v] = nxt[v];
    }
  }

  float* op = out + ((size_t)g * GT + t) * DM + d0;
  if (direct) {
#pragma unroll
    for (int v = 0; v < 8; ++v)
      *(float4*)&op[v * 4] =
          make_float4(acc[v * 4], acc[v * 4 + 1], acc[v * 4 + 2], acc[v * 4 + 3]);
  } else {
#pragma unroll
    for (int v = 0; v < 8; ++v) {
      float4 o = *(float4*)&op[v * 4];
      o.x += acc[v * 4]; o.y += acc[v * 4 + 1];
      o.z += acc[v * 4 + 2]; o.w += acc[v * 4 + 3];
      *(float4*)&op[v * 4] = o;
    }
  }
}

extern "C" void kernel_launch(void* const* d_in, const int* in_sizes, int n_in,
                              void* d_out, int out_size, void* d_ws, size_t ws_size,
                              hipStream_t stream) {
  const float* x  = (const float*)d_in[0];
  const float* Wc = (const float*)d_in[1];
  const float* bc = (const float*)d_in[2];
  const float* W1 = (const float*)d_in[3];
  const float* b1 = (const float*)d_in[4];
  const float* W2 = (const float*)d_in[5];
  const float* b2 = (const float*)d_in[6];
  float* out = (float*)d_out;

  // ws layout (offsets in bytes):
  //   0      sel      256 KB
  //   256K   flags    256 KB (65536 u32, worst-case all columns)
  //   512K   cntr     4 B
  //   768K   Wchf     256 KB
  //   1M     Wclf     256 KB
  //   2M     innerb   4 MB
  //   6M     W2f      8.4 MB
  //   15M    W1f      8.4 MB   (dead after kBm)
  //   24M    xb(=xh)  33.5 MB  (dead after kBm)
  //   15M    Rb       134 MB   (overlaps W1f/xb: both dead before kC1)
  unsigned int* sel    = (unsigned int*)d_ws;
  unsigned int* flags  = (unsigned int*)((char*)d_ws + (256u << 10));
  unsigned int* cntr   = (unsigned int*)((char*)d_ws + (512u << 10));
  unsigned short* Wchf = (unsigned short*)((char*)d_ws + (768u << 10));
  unsigned short* Wclf = (unsigned short*)((char*)d_ws + (1u << 20));
  unsigned short* innerb = (unsigned short*)((char*)d_ws + (2u << 20));
  unsigned short* W2f  = (unsigned short*)((char*)d_ws + (6u << 20));
  unsigned short* W1f  = (unsigned short*)((char*)d_ws + (15u << 20));
  unsigned short* xb   = (unsigned short*)((char*)d_ws + (24u << 20));
  unsigned short* Rb   = (unsigned short*)((char*)d_ws + (15u << 20));

  int Ec = 128;
  while (Ec > 1 && (15u << 20) + (size_t)NGRP * Ec * DM * 2 > ws_size) Ec >>= 1;
  const int NC = NES / Ec;

  hipMemsetAsync(cntr, 0, 4, stream);
  if (NC > 1)
    hipMemsetAsync(d_out, 0, (size_t)out_size * sizeof(float), stream);
  kW<<<4160, 256, 0, stream>>>(W1, W2, Wc, W1f, W2f, Wchf, Wclf);
  kLg<<<NGRP, 1024, 0, stream>>>(x, Wchf, Wclf, bc, xb, sel, flags, cntr);
  kFix<<<1024, 64, 0, stream>>>(x, Wc, bc, sel, flags, cntr);
  kBm<<<NGRP, 256, 0, stream>>>(xb, W1f, b1, sel, innerb);
  for (int c = 0; c < NC; ++c) {
    kC1<<<Ec * 32, 256, 0, stream>>>(innerb, W2f, b2, Rb, c * Ec, Ec);
    kC2<<<NGRP * 4, 256, 0, stream>>>(Rb, sel, out, c * Ec, Ec, NC == 1);
  }
}

// Round 13
// 213.844 us; speedup vs baseline: 1.1720x; 1.1720x over previous
//
#include <hip/hip_runtime.h>
#include <hip/hip_bf16.h>

// BatchSplitFF: DM=1024, NEXPERTS=32, SETS=4 (ES=128 pairs), ESIZE=32, B=2, S=8192
#define DM   1024
#define NES  128
#define GT   32
#define NGRP 512
#define FSZ  32
#define MARGIN_EPS 1e-3f   // > 4x deterministic bound on 3-term bf16-split error

typedef float f32x4 __attribute__((ext_vector_type(4)));
typedef short s16x8 __attribute__((ext_vector_type(8)));

// async global->LDS, 16B per lane; LDS dest is wave-uniform base + lane*16.
#define GL2LDS(gp, lp) __builtin_amdgcn_global_load_lds(                      \
    (const __attribute__((address_space(1))) void*)(gp),                     \
    (__attribute__((address_space(3))) void*)(lp), 16, 0, 0)

__device__ inline unsigned short f2bf(float f) {   // RNE f32->bf16
  union { float f; unsigned int u; } x; x.f = f;
  unsigned int r = x.u + 0x7fffu + ((x.u >> 16) & 1u);
  return (unsigned short)(r >> 16);
}
__device__ inline float bf2f(unsigned short h) {
  union { unsigned int u; float f; } x; x.u = ((unsigned int)h) << 16;
  return x.f;
}

// ---------------------------------------------------------------------------
// kW: merged weight repack. [0,2048): W1 -> bf16 B-frag (K=d, N=f).
// [2048,4096): W2 -> bf16 B-frag (K=f, N=d). [4096,4160): Wc -> hi/lo bf16
// B-frag (K=d, N=es). Unchanged (proven).
// ---------------------------------------------------------------------------
__global__ __launch_bounds__(256) void kW(const float* __restrict__ W1,
                                          const float* __restrict__ W2,
                                          const float* __restrict__ Wc,
                                          unsigned short* __restrict__ W1f,
                                          unsigned short* __restrict__ W2f,
                                          unsigned short* __restrict__ Wchf,
                                          unsigned short* __restrict__ Wclf) {
  const int bid = blockIdx.x;
  if (bid < 2048) {
    int idx = bid * 256 + threadIdx.x;             // (es, kt, nh, lane)
    int l = idx & 63, nh = (idx >> 6) & 1, kt = (idx >> 7) & 31, es = idx >> 12;
    const float* src = W1 + ((size_t)es * DM + kt * 32 + (l >> 4) * 8) * FSZ
                          + nh * 16 + (l & 15);
    s16x8 v;
#pragma unroll
    for (int i = 0; i < 8; ++i) v[i] = (short)f2bf(src[(size_t)i * FSZ]);
    *(s16x8*)(W1f + (size_t)idx * 8) = v;
  } else if (bid < 4096) {
    int idx = (bid - 2048) * 256 + threadIdx.x;    // (es, dt, lane)
    int l = idx & 63, dt = (idx >> 6) & 63, es = idx >> 12;
    const float* src = W2 + ((size_t)es * DM + dt * 16 + (l & 15)) * FSZ + (l >> 4) * 8;
    float4 a = *(const float4*)src;
    float4 b = *(const float4*)(src + 4);
    s16x8 v;
    v[0] = (short)f2bf(a.x); v[1] = (short)f2bf(a.y);
    v[2] = (short)f2bf(a.z); v[3] = (short)f2bf(a.w);
    v[4] = (short)f2bf(b.x); v[5] = (short)f2bf(b.y);
    v[6] = (short)f2bf(b.z); v[7] = (short)f2bf(b.w);
    *(s16x8*)(W2f + (size_t)idx * 8) = v;
  } else {
    int idx = (bid - 4096) * 256 + threadIdx.x;    // (kt, nt, lane) in [0,16384)
    int l = idx & 63, nt = (idx >> 6) & 7, kt = idx >> 9;
    const float* src = Wc + (size_t)(kt * 32 + (l >> 4) * 8) * NES + nt * 16 + (l & 15);
    s16x8 h, lo;
#pragma unroll
    for (int i = 0; i < 8; ++i) {
      float v = src[(size_t)i * NES];
      unsigned short hh = f2bf(v);
      h[i]  = (short)hh;
      lo[i] = (short)f2bf(v - bf2f(hh));
    }
    *(s16x8*)(Wchf + (size_t)idx * 8) = h;
    *(s16x8*)(Wclf + (size_t)idx * 8) = lo;
  }
}

// ---------------------------------------------------------------------------
// kLg v5: r11's 8-wave tiling (wt=w&1 m-tile, we=w>>1 es-32 tile, 6 MFMA/kt,
// per-column chain BIT-IDENTICAL) + x staged through LDS once per block
// (kills r12's 8x L2/L3 x-read redundancy). global_load_lds writes linearly,
// so the GLOBAL source is pre-swizzled by 16B-block b^(row&7) and ds_read
// applies the same XOR (rule #21; conflict-free per 8-lane group).
// ---------------------------------------------------------------------------
__global__ __launch_bounds__(512, 4) void kLg(const float* __restrict__ x,
                                              const unsigned short* __restrict__ Wchf,
                                              const unsigned short* __restrict__ Wclf,
                                              const float* __restrict__ bc,
                                              unsigned short* __restrict__ xh,
                                              unsigned int* __restrict__ sel,
                                              unsigned int* __restrict__ flags,
                                              unsigned int* __restrict__ cnt) {
  __shared__ float lg[GT * NES];                   // 16 KB
  __shared__ float xsA[GT * 32];                   // 4 KB staged x slab
  __shared__ float xsB[GT * 32];                   // 4 KB (double buffer)
  const int g   = blockIdx.x;
  const int tid = threadIdx.x;
  const int l   = tid & 63, w = tid >> 6;          // 8 waves
  const int wt  = w & 1, we = w >> 1;              // m-tile / es-32-tile [0,4)
  const int r15 = l & 15, q = l >> 4;
  const int t   = wt * 16 + r15;                   // token row this lane owns
  const int s   = t & 7;                           // read-side swizzle key
  const float* xg = x + (size_t)g * GT * DM;
  unsigned short* xhrow = xh + ((size_t)(g * GT + t)) * DM + q * 8;
  const unsigned short* Bh_base = Wchf + ((size_t)(we * 2) * 64 + l) * 8;
  const unsigned short* Bl_base = Wclf + ((size_t)(we * 2) * 64 + l) * 8;
  // per-kt B stride in shorts: 8 frag-groups * 64 lanes * 8 = 4096

  // staging roles (waves 0-3, inst w): LDS rows w*8+(l>>3), block p = l&7.
  // LDS position p holds global 16B-block p^(row&7)  (XOR involution).
  const int srow = w * 8 + (l >> 3);
  const int sblk = (l & 7) ^ (srow & 7);
  const float* sgp = xg + (size_t)srow * DM + sblk * 4;

  f32x4 acc0 = {0.f, 0.f, 0.f, 0.f}, acc1 = {0.f, 0.f, 0.f, 0.f};

  if (w < 4) GL2LDS(sgp, xsA + w * 256);           // stage kt=0
  asm volatile("s_waitcnt vmcnt(0)" ::: "memory");
  __syncthreads();

  // B depth-1 register pipeline
  s16x8 Bh0 = *(const s16x8*)(Bh_base);
  s16x8 Bl0 = *(const s16x8*)(Bl_base);
  s16x8 Bh1 = *(const s16x8*)(Bh_base + 512);
  s16x8 Bl1 = *(const s16x8*)(Bl_base + 512);

  const int off0 = t * 32 + (((q * 2) ^ s) * 4);   // swizzled f32 offsets
  const int off1 = t * 32 + (((q * 2 + 1) ^ s) * 4);

  for (int kt = 0; kt < 32; ++kt) {
    const float* buf = (kt & 1) ? xsB : xsA;
    if (kt < 31 && w < 4)
      GL2LDS(sgp + (kt + 1) * 32, (kt & 1) ? (xsA + w * 256) : (xsB + w * 256));

    const int ktn = (kt < 31) ? kt + 1 : 31;       // clamped B prefetch
    s16x8 nBh0 = *(const s16x8*)(Bh_base + (size_t)ktn * 4096);
    s16x8 nBl0 = *(const s16x8*)(Bl_base + (size_t)ktn * 4096);
    s16x8 nBh1 = *(const s16x8*)(Bh_base + (size_t)ktn * 4096 + 512);
    s16x8 nBl1 = *(const s16x8*)(Bl_base + (size_t)ktn * 4096 + 512);

    f32x4 va = *(const f32x4*)&buf[off0];          // x[t][kt*32+q*8 .. +4]
    f32x4 vb = *(const f32x4*)&buf[off1];          // next 4
    float v[8] = {va.x, va.y, va.z, va.w, vb.x, vb.y, vb.z, vb.w};
    s16x8 Ah, Al;
#pragma unroll
    for (int k = 0; k < 8; ++k) {
      unsigned short h = f2bf(v[k]);
      Ah[k] = (short)h;
      Al[k] = (short)f2bf(v[k] - bf2f(h));
    }
    if (we == 0) *(s16x8*)(xhrow + kt * 32) = Ah;  // xh emission (once/row/kt)

    // MFMA: hh, lh, hl per accumulator (r9-r12 order, proven)
    acc0 = __builtin_amdgcn_mfma_f32_16x16x32_bf16(Ah, Bh0, acc0, 0, 0, 0);
    acc0 = __builtin_amdgcn_mfma_f32_16x16x32_bf16(Al, Bh0, acc0, 0, 0, 0);
    acc0 = __builtin_amdgcn_mfma_f32_16x16x32_bf16(Ah, Bl0, acc0, 0, 0, 0);
    acc1 = __builtin_amdgcn_mfma_f32_16x16x32_bf16(Ah, Bh1, acc1, 0, 0, 0);
    acc1 = __builtin_amdgcn_mfma_f32_16x16x32_bf16(Al, Bh1, acc1, 0, 0, 0);
    acc1 = __builtin_amdgcn_mfma_f32_16x16x32_bf16(Ah, Bl1, acc1, 0, 0, 0);

    Bh0 = nBh0; Bl0 = nBl0; Bh1 = nBh1; Bl1 = nBl1;
    asm volatile("s_waitcnt vmcnt(0)" ::: "memory");
    __syncthreads();                               // next slab resident
  }

#pragma unroll
  for (int r = 0; r < 4; ++r) {                    // C/D: row=(lane>>4)*4+reg
    const int tt = wt * 16 + q * 4 + r;
    lg[tt * NES + we * 32 + r15]      = acc0[r];
    lg[tt * NES + we * 32 + 16 + r15] = acc1[r];
  }
  __syncthreads();

  if (tid < NES) {                                 // identical to r9-r12 (proven)
    const int es = tid;
    const float bce = bc[es];
    float m1 = -INFINITY, m2 = -INFINITY;
    int am = 0;
    for (int tt = 0; tt < GT; ++tt) {
      float v = (lg[tt * NES + es] + bce) + (float)((double)tt * (1e-6 / 31.0));
      if (v > m1) { m2 = m1; m1 = v; am = tt; }
      else if (v > m2) m2 = v;
    }
    sel[(size_t)g * NES + es] = 1u << am;
    if (!(m1 - m2 > MARGIN_EPS)) {                 // narrow margin (or NaN): exact pass
      unsigned int p = atomicAdd(cnt, 1u);
      flags[p] = ((unsigned int)g << 7) | (unsigned int)es;
    }
  }
}

// ---------------------------------------------------------------------------
// kFix: exact f32 recompute for flagged columns, BIT-IDENTICAL to the r1-r7
// chain (unchanged, proven).
// ---------------------------------------------------------------------------
__global__ __launch_bounds__(64) void kFix(const float* __restrict__ x,
                                           const float* __restrict__ Wc,
                                           const float* __restrict__ bc,
                                           unsigned int* __restrict__ sel,
                                           const unsigned int* __restrict__ flags,
                                           const unsigned int* __restrict__ cnt) {
  __shared__ float v[GT];
  const int tid = threadIdx.x;
  const unsigned int n = *cnt;
  for (unsigned int i = blockIdx.x; i < n; i += gridDim.x) {
    const unsigned int f = flags[i];
    const int g = (int)(f >> 7), es = (int)(f & 127u);
    if (tid < GT) {
      const float* xr = x + ((size_t)g * GT + tid) * DM;
      const float* wcol = Wc + es;
      float acc = 0.f;
      for (int c = 0; c < 16; ++c) {
        float part = 0.f;
#pragma unroll 4
        for (int s = 0; s < 16; ++s) {
          const int d0 = c * 64 + s * 4;
          float4 xv = *(const float4*)&xr[d0];
          float w0 = wcol[(size_t)(d0 + 0) * NES];
          float w1 = wcol[(size_t)(d0 + 1) * NES];
          float w2 = wcol[(size_t)(d0 + 2) * NES];
          float w3 = wcol[(size_t)(d0 + 3) * NES];
          part = fmaf(xv.x, w0, part);             // dd-sequential (r1 order)
          part = fmaf(xv.y, w1, part);
          part = fmaf(xv.z, w2, part);
          part = fmaf(xv.w, w3, part);
        }
        acc += part;
      }
      v[tid] = (acc + bc[es]) + (float)((double)tid * (1e-6 / 31.0));
    }
    __syncthreads();
    if (tid == 0) {
      float m = -INFINITY;
      for (int t = 0; t < GT; ++t) m = fmaxf(m, v[t]);
      unsigned int msk = 0u;
      for (int t = 0; t < GT; ++t) if (v[t] == m) msk |= (1u << t);
      sel[(size_t)g * NES + es] = msk;
    }
    __syncthreads();
  }
}

// ---------------------------------------------------------------------------
// kBm: inner = relu(xsel . W1[es] + b1[es]) via MFMA (unchanged, proven).
// ---------------------------------------------------------------------------
__global__ __launch_bounds__(256, 2) void kBm(const unsigned short* __restrict__ xb,
                                              const unsigned short* __restrict__ W1f,
                                              const float* __restrict__ b1,
                                              const unsigned int* __restrict__ sel,
                                              unsigned short* __restrict__ innerb) {
  __shared__ unsigned short As[128 * 128];   // [row][k] bf16, byte^((row&7)<<4)
  __shared__ int tokL[128];
  __shared__ unsigned int mulL[128];
  const int bid = blockIdx.x;
  const int es = bid >> 2, g0 = (bid & 3) * 128;
  const int tid = threadIdx.x;
  const int l = tid & 63, w = tid >> 6;
  const int r15 = l & 15, q = l >> 4;
  const int mw = w * 32;

  if (tid < 128) {
    unsigned int m = sel[(size_t)(g0 + tid) * NES + es];
    tokL[tid] = (g0 + tid) * GT + (__ffs(m) - 1);
    mulL[tid] = (m & (m - 1)) ? m : 0u;
  }

  const int r = tid >> 1, p = tid & 1;
  const int swz = (r & 7) << 4;
  const unsigned int dbase = (unsigned int)r * 256 + (unsigned int)p * 128;

  f32x4 acc[2][2];
#pragma unroll
  for (int i = 0; i < 2; ++i)
#pragma unroll
    for (int j = 0; j < 2; ++j) acc[i][j] = (f32x4){0.f, 0.f, 0.f, 0.f};

  for (int c = 0; c < 8; ++c) {
    __syncthreads();
    unsigned int mm = mulL[r];
    if (!mm) {
      const unsigned short* src = xb + (size_t)tokL[r] * DM + c * 128 + p * 64;
#pragma unroll
      for (int j = 0; j < 8; ++j) {
        s16x8 v = *(const s16x8*)(src + j * 8);
        *(s16x8*)((char*)As + ((dbase + j * 16) ^ swz)) = v;
      }
    } else {
      size_t grow = (size_t)(g0 + r) * GT;
#pragma unroll
      for (int j = 0; j < 8; ++j) {
        float av[8] = {0.f, 0.f, 0.f, 0.f, 0.f, 0.f, 0.f, 0.f};
        unsigned int m2 = mm;
        while (m2) {
          int tt = __ffs(m2) - 1; m2 &= m2 - 1;
          s16x8 v = *(const s16x8*)(xb + (grow + tt) * DM + c * 128 + p * 64 + j * 8);
#pragma unroll
          for (int k = 0; k < 8; ++k) av[k] += bf2f((unsigned short)v[k]);
        }
        s16x8 o;
#pragma unroll
        for (int k = 0; k < 8; ++k) o[k] = (short)f2bf(av[k]);
        *(s16x8*)((char*)As + ((dbase + j * 16) ^ swz)) = o;
      }
    }
    __syncthreads();

#pragma unroll
    for (int s = 0; s < 4; ++s) {
      const int ks = c * 4 + s;
      const unsigned short* bp = W1f + ((size_t)es * 32 + ks) * 1024 + l * 8;
      s16x8 bf0 = *(const s16x8*)bp;
      s16x8 bf1 = *(const s16x8*)(bp + 512);
      const int row0 = mw + r15, row1 = mw + 16 + r15;
      s16x8 a0 = *(const s16x8*)((char*)As +
                   (((unsigned)row0 * 256 + s * 64 + q * 16) ^ ((row0 & 7) << 4)));
      s16x8 a1 = *(const s16x8*)((char*)As +
                   (((unsigned)row1 * 256 + s * 64 + q * 16) ^ ((row1 & 7) << 4)));
      acc[0][0] = __builtin_amdgcn_mfma_f32_16x16x32_bf16(a0, bf0, acc[0][0], 0, 0, 0);
      acc[0][1] = __builtin_amdgcn_mfma_f32_16x16x32_bf16(a0, bf1, acc[0][1], 0, 0, 0);
      acc[1][0] = __builtin_amdgcn_mfma_f32_16x16x32_bf16(a1, bf0, acc[1][0], 0, 0, 0);
      acc[1][1] = __builtin_amdgcn_mfma_f32_16x16x32_bf16(a1, bf1, acc[1][1], 0, 0, 0);
    }
  }

  float bia0 = b1[es * FSZ + r15];
  float bia1 = b1[es * FSZ + 16 + r15];
#pragma unroll
  for (int i = 0; i < 2; ++i)
#pragma unroll
    for (int rr = 0; rr < 4; ++rr) {
      int g = g0 + mw + i * 16 + q * 4 + rr;
      unsigned short* op = innerb + ((size_t)es * NGRP + g) * FSZ;
      op[r15]      = f2bf(fmaxf(acc[i][0][rr] + bia0, 0.f));
      op[16 + r15] = f2bf(fmaxf(acc[i][1][rr] + bia1, 0.f));
    }
}

// ---------------------------------------------------------------------------
// kC1: per-es dense GEMM (512g x 32f).(32f x 1024d) -> Rb bf16 [g][Ec][d],
// b2 folded (unchanged, proven).
// ---------------------------------------------------------------------------
__global__ __launch_bounds__(256) void kC1(const unsigned short* __restrict__ innerb,
                                           const unsigned short* __restrict__ W2f,
                                           const float* __restrict__ b2,
                                           unsigned short* __restrict__ Rb,
                                           int es0, int Ec) {
  const int bid = blockIdx.x;
  const int esl = bid >> 5;
  const int es  = es0 + esl;
  const int mt  = (bid >> 3) & 3;
  const int nt  = bid & 7;
  const int tid = threadIdx.x;
  const int l = tid & 63, w = tid >> 6;
  const int r15 = l & 15, q = l >> 4;
  const int g0 = mt * 128 + (w >> 1) * 64;
  const int n0 = nt * 128 + (w & 1) * 64;

  const unsigned short* Ab = innerb + ((size_t)es * NGRP + g0 + r15) * FSZ + q * 8;
  const unsigned short* Bb = W2f + (((size_t)es * 64 + (n0 >> 4)) * 64 + l) * 8;
  s16x8 a[4], b[4];
#pragma unroll
  for (int i = 0; i < 4; ++i) a[i] = *(const s16x8*)(Ab + (size_t)i * 16 * FSZ);
#pragma unroll
  for (int j = 0; j < 4; ++j) b[j] = *(const s16x8*)(Bb + (size_t)j * 64 * 8);

  const f32x4 z = {0.f, 0.f, 0.f, 0.f};
  f32x4 acc[4][4];
#pragma unroll
  for (int i = 0; i < 4; ++i)
#pragma unroll
    for (int j = 0; j < 4; ++j)
      acc[i][j] = __builtin_amdgcn_mfma_f32_16x16x32_bf16(a[i], b[j], z, 0, 0, 0);

#pragma unroll
  for (int j = 0; j < 4; ++j) {
    const int col = n0 + j * 16 + r15;
    const float b2v = b2[(size_t)es * DM + col];
#pragma unroll
    for (int i = 0; i < 4; ++i) {
#pragma unroll
      for (int r = 0; r < 4; ++r) {
        const int g = g0 + i * 16 + q * 4 + r;
        Rb[((size_t)g * Ec + esl) * DM + col] = f2bf(acc[i][j][r] + b2v);
      }
    }
  }
}

// ---------------------------------------------------------------------------
// kC2: per-(group, d-quarter) gather-combine (unchanged, proven).
// ---------------------------------------------------------------------------
__global__ __launch_bounds__(256) void kC2(const unsigned short* __restrict__ Rb,
                                           const unsigned int* __restrict__ sel,
                                           float* __restrict__ out,
                                           int es0, int Ec, int direct) {
  __shared__ unsigned int cnt[32];
  __shared__ unsigned char list[32][128];
  const int bid = blockIdx.x;
  const int g = bid >> 2, dq = bid & 3;
  const int tid = threadIdx.x;
  if (tid < 32) cnt[tid] = 0;
  __syncthreads();
  if (tid < Ec) {
    unsigned int m = sel[(size_t)g * NES + es0 + tid];
    while (m) { int t = __ffs(m) - 1; m &= m - 1;
      unsigned int p = atomicAdd(&cnt[t], 1u);
      list[t][p] = (unsigned char)tid; }
  }
  __syncthreads();
  const int t = tid >> 3, part = tid & 7;
  const int d0 = dq * 256 + part * 32;
  const int n = (int)cnt[t];
  const unsigned short* base = Rb + (size_t)g * Ec * DM + d0;

  float acc[32];
#pragma unroll
  for (int i = 0; i < 32; ++i) acc[i] = 0.f;

  s16x8 cur[4];
  if (n) {
    const unsigned short* r = base + (size_t)list[t][0] * DM;
#pragma unroll
    for (int v = 0; v < 4; ++v) cur[v] = *(const s16x8*)(r + v * 8);
  }
  for (int e = 0; e < n; ++e) {
    s16x8 nxt[4];
    const bool more = (e + 1 < n);
    if (more) {
      const unsigned short* r = base + (size_t)list[t][e + 1] * DM;
#pragma unroll
      for (int v = 0; v < 4; ++v) nxt[v] = *(const s16x8*)(r + v * 8);
    }
#pragma unroll
    for (int v = 0; v < 4; ++v)
#pragma unroll
      for (int k = 0; k < 8; ++k)
        acc[v * 8 + k] += bf2f((unsigned short)cur[v][k]);
    if (more) {
#pragma unroll
      for (int v = 0; v < 4; ++v) cur[v] = nxt[v];
    }
  }

  float* op = out + ((size_t)g * GT + t) * DM + d0;
  if (direct) {
#pragma unroll
    for (int v = 0; v < 8; ++v)
      *(float4*)&op[v * 4] =
          make_float4(acc[v * 4], acc[v * 4 + 1], acc[v * 4 + 2], acc[v * 4 + 3]);
  } else {
#pragma unroll
    for (int v = 0; v < 8; ++v) {
      float4 o = *(float4*)&op[v * 4];
      o.x += acc[v * 4]; o.y += acc[v * 4 + 1];
      o.z += acc[v * 4 + 2]; o.w += acc[v * 4 + 3];
      *(float4*)&op[v * 4] = o;
    }
  }
}

extern "C" void kernel_launch(void* const* d_in, const int* in_sizes, int n_in,
                              void* d_out, int out_size, void* d_ws, size_t ws_size,
                              hipStream_t stream) {
  const float* x  = (const float*)d_in[0];
  const float* Wc = (const float*)d_in[1];
  const float* bc = (const float*)d_in[2];
  const float* W1 = (const float*)d_in[3];
  const float* b1 = (const float*)d_in[4];
  const float* W2 = (const float*)d_in[5];
  const float* b2 = (const float*)d_in[6];
  float* out = (float*)d_out;

  // ws layout (offsets in bytes):
  //   0      sel      256 KB
  //   256K   flags    256 KB (65536 u32, worst-case all columns)
  //   512K   cntr     4 B
  //   768K   Wchf     256 KB
  //   1M     Wclf     256 KB
  //   2M     innerb   4 MB
  //   6M     W2f      8.4 MB
  //   15M    W1f      8.4 MB   (dead after kBm)
  //   24M    xb(=xh)  33.5 MB  (dead after kBm)
  //   15M    Rb       134 MB   (overlaps W1f/xb: both dead before kC1)
  unsigned int* sel    = (unsigned int*)d_ws;
  unsigned int* flags  = (unsigned int*)((char*)d_ws + (256u << 10));
  unsigned int* cntr   = (unsigned int*)((char*)d_ws + (512u << 10));
  unsigned short* Wchf = (unsigned short*)((char*)d_ws + (768u << 10));
  unsigned short* Wclf = (unsigned short*)((char*)d_ws + (1u << 20));
  unsigned short* innerb = (unsigned short*)((char*)d_ws + (2u << 20));
  unsigned short* W2f  = (unsigned short*)((char*)d_ws + (6u << 20));
  unsigned short* W1f  = (unsigned short*)((char*)d_ws + (15u << 20));
  unsigned short* xb   = (unsigned short*)((char*)d_ws + (24u << 20));
  unsigned short* Rb   = (unsigned short*)((char*)d_ws + (15u << 20));

  int Ec = 128;
  while (Ec > 1 && (15u << 20) + (size_t)NGRP * Ec * DM * 2 > ws_size) Ec >>= 1;
  const int NC = NES / Ec;

  hipMemsetAsync(cntr, 0, 4, stream);
  if (NC > 1)
    hipMemsetAsync(d_out, 0, (size_t)out_size * sizeof(float), stream);
  kW<<<4160, 256, 0, stream>>>(W1, W2, Wc, W1f, W2f, Wchf, Wclf);
  kLg<<<NGRP, 512, 0, stream>>>(x, Wchf, Wclf, bc, xb, sel, flags, cntr);
  kFix<<<1024, 64, 0, stream>>>(x, Wc, bc, sel, flags, cntr);
  kBm<<<NGRP, 256, 0, stream>>>(xb, W1f, b1, sel, innerb);
  for (int c = 0; c < NC; ++c) {
    kC1<<<Ec * 32, 256, 0, stream>>>(innerb, W2f, b2, Rb, c * Ec, Ec);
    kC2<<<NGRP * 4, 256, 0, stream>>>(Rb, sel, out, c * Ec, Ec, NC == 1);
  }
}